// Round 1
// baseline (78.135 us; speedup 1.0000x reference)
//
#include <hip/hip_runtime.h>

// Problem: B=4, N=384, DX=2, DR=128, H=128, DOUT=64
// out[b,n,m,o] = relu( (x_ctx[b,n]-x_ctx[b,m]) @ W1[0:2] + r[b] @ W1[2:130] + b1 ) @ W2 + b2
//
// Decomposition:
//   c[b,k]  = b1[k] + sum_d r[b,d]*W1[2+d,k]          (prep kernel A)
//   u[b,i,k]= x[b,i,0]*W1[0,k] + x[b,i,1]*W1[1,k]     (prep kernel B)
//   v[b,i,k]= u[b,i,k] + c[b,k]
//   h[b,n,m,k] = relu(v[b,n,k] - u[b,m,k])            (main, fp32 -> bf16)
//   out = h @ W2 (bf16 MFMA 16x16x32, fp32 accum) + b2
//
// ws layout (bytes):
//   [0,2048)              c[4][128] f32
//   [2048, 788480)        u[4][384][128] f32
//   [788480, 1574912)     v[4][384][128] f32
//   [1574912, 1591296)    w2t[64][128] bf16   (W2 transposed, o-major)

typedef __attribute__((ext_vector_type(8))) __bf16 bf16x8;
typedef __attribute__((ext_vector_type(4))) __bf16 bf16x4;
typedef __attribute__((ext_vector_type(4))) float f32x4;

#define B_    4
#define N_    384
#define H_    128
#define DOUT_ 64

__global__ __launch_bounds__(256) void prep_c_w2(
    const float* __restrict__ r, const float* __restrict__ W1,
    const float* __restrict__ b1, const float* __restrict__ W2,
    float* __restrict__ c, __bf16* __restrict__ w2t)
{
    int bid = blockIdx.x;
    int tid = threadIdx.x;
    if (bid < 4) {
        if (tid < H_) {
            float acc = b1[tid];
            const float* w  = W1 + 2 * H_ + tid;   // W1[(2+d)*128 + k]
            const float* rb = r + bid * 128;
            #pragma unroll 8
            for (int d = 0; d < 128; ++d) acc += rb[d] * w[d * H_];
            c[bid * H_ + tid] = acc;
        }
    } else {
        // w2t[o][k] = bf16(W2[k][o])
        for (int i = tid; i < DOUT_ * H_; i += 256) {
            int o = i >> 7, k = i & 127;
            w2t[i] = (__bf16)W2[k * DOUT_ + o];
        }
    }
}

__global__ __launch_bounds__(128) void prep_uv(
    const float* __restrict__ xctx, const float* __restrict__ W1,
    const float* __restrict__ c, float* __restrict__ u, float* __restrict__ v)
{
    int bid = blockIdx.x;           // b*384 + i
    int b = bid / N_;
    int k = threadIdx.x;
    float x0 = xctx[bid * 2], x1 = xctx[bid * 2 + 1];
    float uu = x0 * W1[k] + x1 * W1[H_ + k];
    u[bid * H_ + k] = uu;
    v[bid * H_ + k] = uu + c[b * H_ + k];
}

// Grid: bid = ((b*64 + ngrp)*6 + mchunk), 1536 blocks x 256 threads (4 waves).
// Wave w owns 16 m's: m = mchunk*64 + w*16 + (lane&15); loops over 6 n's.
// MFMA orientation: A = W2^T tile (rows=o), B = h (cols=m) -> D[o][m];
// lane stores 4 consecutive o's as one dwordx4.
__global__ __launch_bounds__(256) void te_main(
    const float* __restrict__ u, const float* __restrict__ v,
    const __bf16* __restrict__ w2t, const float* __restrict__ b2,
    float* __restrict__ out)
{
    int tid  = threadIdx.x;
    int wave = tid >> 6, lane = tid & 63;
    int g  = lane >> 4;        // lane group 0..3
    int rl = lane & 15;        // row-in-group

    int bid    = blockIdx.x;
    int mchunk = bid % 6;
    int t      = bid / 6;
    int ngrp   = t & 63;
    int b      = t >> 6;

    int m = mchunk * 64 + wave * 16 + rl;   // this lane's pair column

    // --- loop-invariant register state ---
    // W2^T fragments: w2f[rt][ks], element j holds W2[kk(ks,j,g)][rt*16+rl]
    // kk = ks*32 + (j>=4)*16 + g*4 + (j&3)
    bf16x8 w2f[4][4];
    #pragma unroll
    for (int rt = 0; rt < 4; ++rt) {
        const __bf16* basep = w2t + (rt * 16 + rl) * H_;
        #pragma unroll
        for (int ks = 0; ks < 4; ++ks) {
            #pragma unroll
            for (int hh = 0; hh < 2; ++hh) {
                bf16x4 q = *reinterpret_cast<const bf16x4*>(basep + ks * 32 + hh * 16 + g * 4);
                #pragma unroll
                for (int j = 0; j < 4; ++j) w2f[rt][ks][hh * 4 + j] = q[j];
            }
        }
    }

    // u[b, m, kk] fragments (fp32), fixed per wave
    f32x4 um[4][2];
    {
        const float* ub = u + (b * N_ + m) * H_;
        #pragma unroll
        for (int ks = 0; ks < 4; ++ks)
            #pragma unroll
            for (int hh = 0; hh < 2; ++hh)
                um[ks][hh] = *reinterpret_cast<const f32x4*>(ub + ks * 32 + hh * 16 + g * 4);
    }

    // b2 fragments for accumulator init: lane's o = rt*16 + g*4 + reg
    f32x4 b2f[4];
    #pragma unroll
    for (int rt = 0; rt < 4; ++rt)
        b2f[rt] = *reinterpret_cast<const f32x4*>(b2 + rt * 16 + g * 4);

    const float* vb   = v + b * N_ * H_;
    size_t outb = (size_t)b * N_ * N_ * DOUT_;

    for (int i = 0; i < 6; ++i) {
        int n = ngrp * 6 + i;
        const float* vn = vb + n * H_;

        // h fragments (B operand): lane holds h[kk][m] for its m
        bf16x8 hf[4];
        #pragma unroll
        for (int ks = 0; ks < 4; ++ks) {
            #pragma unroll
            for (int hh = 0; hh < 2; ++hh) {
                f32x4 vv = *reinterpret_cast<const f32x4*>(vn + ks * 32 + hh * 16 + g * 4);
                #pragma unroll
                for (int j = 0; j < 4; ++j) {
                    float d  = vv[j] - um[ks][hh][j];
                    float hv = d > 0.f ? d : 0.f;
                    hf[ks][hh * 4 + j] = (__bf16)hv;
                }
            }
        }

        f32x4 acc[4];
        #pragma unroll
        for (int rt = 0; rt < 4; ++rt) acc[rt] = b2f[rt];

        #pragma unroll
        for (int ks = 0; ks < 4; ++ks)
            #pragma unroll
            for (int rt = 0; rt < 4; ++rt)
                acc[rt] = __builtin_amdgcn_mfma_f32_16x16x32_bf16(w2f[rt][ks], hf[ks], acc[rt], 0, 0, 0);

        float* op = out + outb + ((size_t)n * N_ + m) * DOUT_ + g * 4;
        #pragma unroll
        for (int rt = 0; rt < 4; ++rt)
            *reinterpret_cast<f32x4*>(op + rt * 16) = acc[rt];
    }
}

extern "C" void kernel_launch(void* const* d_in, const int* in_sizes, int n_in,
                              void* d_out, int out_size, void* d_ws, size_t ws_size,
                              hipStream_t stream)
{
    const float* r    = (const float*)d_in[0];
    const float* xctx = (const float*)d_in[1];
    // d_in[2] = y_ctx (unused), d_in[3] = x_trg (unused)
    const float* W1 = (const float*)d_in[4];
    const float* b1 = (const float*)d_in[5];
    const float* W2 = (const float*)d_in[6];
    const float* b2 = (const float*)d_in[7];
    float* out = (float*)d_out;

    char* ws = (char*)d_ws;   // needs ~1.6 MB
    float*  c   = (float*)(ws);
    float*  u   = (float*)(ws + 2048);
    float*  v   = (float*)(ws + 2048 + 786432);
    __bf16* w2t = (__bf16*)(ws + 2048 + 2 * 786432);

    hipLaunchKernelGGL(prep_c_w2, dim3(5), dim3(256), 0, stream, r, W1, b1, W2, c, w2t);
    hipLaunchKernelGGL(prep_uv, dim3(B_ * N_), dim3(128), 0, stream, xctx, W1, c, u, v);
    hipLaunchKernelGGL(te_main, dim3(B_ * 6 * 64), dim3(256), 0, stream, u, v, w2t, b2, out);
}

// Round 2
// 57.343 us; speedup vs baseline: 1.3626x; 1.3626x over previous
//
#include <hip/hip_runtime.h>

// Problem: B=4, N=384, DX=2, DR=128, H=128, DOUT=64
// out[b,n,m,o] = relu( (x_ctx[b,n]-x_ctx[b,m]) @ W1[0:2] + r[b] @ W1[2:130] + b1 ) @ W2 + b2
//
// Decomposition:
//   c[b,k]  = b1[k] + sum_d r[b,d]*W1[2+d,k]          (prep kernel A)
//   u[b,i,k]= x[b,i,0]*W1[0,k] + x[b,i,1]*W1[1,k]     (prep kernel B)
//   v[b,i,k]= u[b,i,k] + c[b,k]
//   h[b,n,m,k] = relu(v[b,n,k] - u[b,m,k])            (main, fp32 -> bf16)
//   out = h @ W2 (bf16 MFMA 16x16x32, fp32 accum) + b2
//
// Round-2 change: v-rows staged in LDS at block start so the main loop has
// ZERO vector-memory loads -> no s_waitcnt vmcnt(0) coupling the loop to
// store retirement (stores are fire-and-forget). Output stores nontemporal.
//
// ws layout (bytes):
//   [0,2048)              c[4][128] f32
//   [2048, 788480)        u[4][384][128] f32
//   [788480, 1574912)     v[4][384][128] f32
//   [1574912, 1591296)    w2t[64][128] bf16   (W2 transposed, o-major)

typedef __attribute__((ext_vector_type(8))) __bf16 bf16x8;
typedef __attribute__((ext_vector_type(4))) __bf16 bf16x4;
typedef __attribute__((ext_vector_type(4))) float f32x4;

#define B_    4
#define N_    384
#define H_    128
#define DOUT_ 64

__global__ __launch_bounds__(256) void prep_c_w2(
    const float* __restrict__ r, const float* __restrict__ W1,
    const float* __restrict__ b1, const float* __restrict__ W2,
    float* __restrict__ c, __bf16* __restrict__ w2t)
{
    int bid = blockIdx.x;
    int tid = threadIdx.x;
    if (bid < 4) {
        if (tid < H_) {
            float acc = b1[tid];
            const float* w  = W1 + 2 * H_ + tid;   // W1[(2+d)*128 + k]
            const float* rb = r + bid * 128;
            #pragma unroll 8
            for (int d = 0; d < 128; ++d) acc += rb[d] * w[d * H_];
            c[bid * H_ + tid] = acc;
        }
    } else {
        // w2t[o][k] = bf16(W2[k][o])
        for (int i = tid; i < DOUT_ * H_; i += 256) {
            int o = i >> 7, k = i & 127;
            w2t[i] = (__bf16)W2[k * DOUT_ + o];
        }
    }
}

__global__ __launch_bounds__(128) void prep_uv(
    const float* __restrict__ xctx, const float* __restrict__ W1,
    const float* __restrict__ c, float* __restrict__ u, float* __restrict__ v)
{
    int bid = blockIdx.x;           // b*384 + i
    int b = bid / N_;
    int k = threadIdx.x;
    float x0 = xctx[bid * 2], x1 = xctx[bid * 2 + 1];
    float uu = x0 * W1[k] + x1 * W1[H_ + k];
    u[bid * H_ + k] = uu;
    v[bid * H_ + k] = uu + c[b * H_ + k];
}

// Grid: bid = ((b*64 + ngrp)*6 + mchunk), 1536 blocks x 256 threads (4 waves).
// Wave w owns 16 m's: m = mchunk*64 + w*16 + (lane&15); loops over 6 n's.
// MFMA orientation: A = W2^T tile (rows=o), B = h (cols=m) -> D[o][m];
// lane stores 4 consecutive o's as one dwordx4.
__global__ __launch_bounds__(256) void te_main(
    const float* __restrict__ u, const float* __restrict__ v,
    const __bf16* __restrict__ w2t, const float* __restrict__ b2,
    float* __restrict__ out)
{
    __shared__ float vlds[6][H_];   // this block's 6 v-rows (3 KB)

    int tid  = threadIdx.x;
    int wave = tid >> 6, lane = tid & 63;
    int g  = lane >> 4;        // lane group 0..3
    int rl = lane & 15;        // row-in-group

    int bid    = blockIdx.x;
    int mchunk = bid % 6;
    int t      = bid / 6;
    int ngrp   = t & 63;
    int b      = t >> 6;

    int m = mchunk * 64 + wave * 16 + rl;   // this lane's pair column

    // ---- stage v rows n = ngrp*6 .. +5 into LDS (192 threads x 16 B) ----
    if (tid < 192) {
        int row  = tid >> 5;           // 0..5
        int col4 = (tid & 31) << 2;    // 0,4,..,124
        *reinterpret_cast<f32x4*>(&vlds[row][col4]) =
            *reinterpret_cast<const f32x4*>(v + ((size_t)(b * N_ + ngrp * 6 + row)) * H_ + col4);
    }

    // --- loop-invariant register state (global loads, waited once) ---
    // W2^T fragments: w2f[rt][ks], element j holds W2[kk(ks,j,g)][rt*16+rl]
    // kk = ks*32 + (j>=4)*16 + g*4 + (j&3)
    bf16x8 w2f[4][4];
    #pragma unroll
    for (int rt = 0; rt < 4; ++rt) {
        const __bf16* basep = w2t + (rt * 16 + rl) * H_;
        #pragma unroll
        for (int ks = 0; ks < 4; ++ks) {
            #pragma unroll
            for (int hh = 0; hh < 2; ++hh) {
                bf16x4 q = *reinterpret_cast<const bf16x4*>(basep + ks * 32 + hh * 16 + g * 4);
                #pragma unroll
                for (int j = 0; j < 4; ++j) w2f[rt][ks][hh * 4 + j] = q[j];
            }
        }
    }

    // u[b, m, kk] fragments (fp32), fixed per wave
    f32x4 um[4][2];
    {
        const float* ub = u + ((size_t)(b * N_ + m)) * H_;
        #pragma unroll
        for (int ks = 0; ks < 4; ++ks)
            #pragma unroll
            for (int hh = 0; hh < 2; ++hh)
                um[ks][hh] = *reinterpret_cast<const f32x4*>(ub + ks * 32 + hh * 16 + g * 4);
    }

    // b2 fragments for accumulator init: lane's o = rt*16 + g*4 + reg
    f32x4 b2f[4];
    #pragma unroll
    for (int rt = 0; rt < 4; ++rt)
        b2f[rt] = *reinterpret_cast<const f32x4*>(b2 + rt * 16 + g * 4);

    __syncthreads();   // vlds ready

    size_t outb = (size_t)b * N_ * N_ * DOUT_;

    // Main loop: ds_read (lgkmcnt) + VALU + MFMA + nontemporal stores.
    // No vector-memory LOADS here -> stores never block the pipeline.
    #pragma unroll 2
    for (int i = 0; i < 6; ++i) {
        int n = ngrp * 6 + i;

        // h fragments (B operand): lane holds h[kk][m] for its m
        bf16x8 hf[4];
        #pragma unroll
        for (int ks = 0; ks < 4; ++ks) {
            #pragma unroll
            for (int hh = 0; hh < 2; ++hh) {
                f32x4 vv = *reinterpret_cast<const f32x4*>(&vlds[i][ks * 32 + hh * 16 + g * 4]);
                #pragma unroll
                for (int j = 0; j < 4; ++j) {
                    float d  = vv[j] - um[ks][hh][j];
                    float hv = d > 0.f ? d : 0.f;
                    hf[ks][hh * 4 + j] = (__bf16)hv;
                }
            }
        }

        f32x4 acc[4];
        #pragma unroll
        for (int rt = 0; rt < 4; ++rt) acc[rt] = b2f[rt];

        #pragma unroll
        for (int ks = 0; ks < 4; ++ks)
            #pragma unroll
            for (int rt = 0; rt < 4; ++rt)
                acc[rt] = __builtin_amdgcn_mfma_f32_16x16x32_bf16(w2f[rt][ks], hf[ks], acc[rt], 0, 0, 0);

        float* op = out + outb + ((size_t)n * N_ + m) * DOUT_ + g * 4;
        #pragma unroll
        for (int rt = 0; rt < 4; ++rt)
            __builtin_nontemporal_store(acc[rt], reinterpret_cast<f32x4*>(op + rt * 16));
    }
}

extern "C" void kernel_launch(void* const* d_in, const int* in_sizes, int n_in,
                              void* d_out, int out_size, void* d_ws, size_t ws_size,
                              hipStream_t stream)
{
    const float* r    = (const float*)d_in[0];
    const float* xctx = (const float*)d_in[1];
    // d_in[2] = y_ctx (unused), d_in[3] = x_trg (unused)
    const float* W1 = (const float*)d_in[4];
    const float* b1 = (const float*)d_in[5];
    const float* W2 = (const float*)d_in[6];
    const float* b2 = (const float*)d_in[7];
    float* out = (float*)d_out;

    char* ws = (char*)d_ws;   // needs ~1.6 MB
    float*  c   = (float*)(ws);
    float*  u   = (float*)(ws + 2048);
    float*  v   = (float*)(ws + 2048 + 786432);
    __bf16* w2t = (__bf16*)(ws + 2048 + 2 * 786432);

    hipLaunchKernelGGL(prep_c_w2, dim3(5), dim3(256), 0, stream, r, W1, b1, W2, c, w2t);
    hipLaunchKernelGGL(prep_uv, dim3(B_ * N_), dim3(128), 0, stream, xctx, W1, c, u, v);
    hipLaunchKernelGGL(te_main, dim3(B_ * 6 * 64), dim3(256), 0, stream, u, v, w2t, b2, out);
}

// Round 3
// 56.028 us; speedup vs baseline: 1.3946x; 1.0235x over previous
//
#include <hip/hip_runtime.h>

// Problem: B=4, N=384, DX=2, DR=128, H=128, DOUT=64
// out[b,n,m,o] = relu( (x_ctx[b,n]-x_ctx[b,m]) @ W1[0:2] + r[b] @ W1[2:130] + b1 ) @ W2 + b2
//
// Decomposition:
//   c[b,k]  = b1[k] + sum_d r[b,d]*W1[2+d,k]          (prep kernel A)
//   u[b,i,k]= x[b,i,0]*W1[0,k] + x[b,i,1]*W1[1,k]     (prep kernel B)
//   v[b,i,k]= u[b,i,k] + c[b,k]
//   h[b,n,m,k] = relu(v[b,n,k] - u[b,m,k])            (main, fp32 -> bf16)
//   out = h @ W2 (bf16 MFMA 16x16x32, fp32 accum) + b2
//
// Round-3 change: output stores were 64B-segments @256B stride (lane&15 = m
// in the MFMA D layout) -> ~2.9 TB/s effective. Now each wave transposes its
// 16m x 64o fp32 tile through a private 4KB LDS region (XOR block swizzle,
// bank-uniform on both sides) and issues 4 x 1KB fully-contiguous dwordx4
// stores per iteration — same access shape as fillBuffer (6.6 TB/s).
// NT flag dropped (let L2 write-combine the stream).

typedef __attribute__((ext_vector_type(8))) __bf16 bf16x8;
typedef __attribute__((ext_vector_type(4))) __bf16 bf16x4;
typedef __attribute__((ext_vector_type(4))) float f32x4;

#define B_    4
#define N_    384
#define H_    128
#define DOUT_ 64

__global__ __launch_bounds__(256) void prep_c_w2(
    const float* __restrict__ r, const float* __restrict__ W1,
    const float* __restrict__ b1, const float* __restrict__ W2,
    float* __restrict__ c, __bf16* __restrict__ w2t)
{
    int bid = blockIdx.x;
    int tid = threadIdx.x;
    if (bid < 4) {
        if (tid < H_) {
            float acc = b1[tid];
            const float* w  = W1 + 2 * H_ + tid;   // W1[(2+d)*128 + k]
            const float* rb = r + bid * 128;
            #pragma unroll 8
            for (int d = 0; d < 128; ++d) acc += rb[d] * w[d * H_];
            c[bid * H_ + tid] = acc;
        }
    } else {
        // w2t[o][k] = bf16(W2[k][o])
        for (int i = tid; i < DOUT_ * H_; i += 256) {
            int o = i >> 7, k = i & 127;
            w2t[i] = (__bf16)W2[k * DOUT_ + o];
        }
    }
}

__global__ __launch_bounds__(128) void prep_uv(
    const float* __restrict__ xctx, const float* __restrict__ W1,
    const float* __restrict__ c, float* __restrict__ u, float* __restrict__ v)
{
    int bid = blockIdx.x;           // b*384 + i
    int b = bid / N_;
    int k = threadIdx.x;
    float x0 = xctx[bid * 2], x1 = xctx[bid * 2 + 1];
    float uu = x0 * W1[k] + x1 * W1[H_ + k];
    u[bid * H_ + k] = uu;
    v[bid * H_ + k] = uu + c[b * H_ + k];
}

// Grid: bid = ((b*64 + ngrp)*6 + mchunk), 1536 blocks x 256 threads (4 waves).
// Wave w owns 16 m's: m = mchunk*64 + w*16 + (lane&15); loops over 6 n's.
// MFMA orientation: A = W2^T tile (rows=o), B = h (cols=m) -> D[o][m].
// Epilogue: per-wave LDS transpose -> 4 x 1KB contiguous stores.
__global__ __launch_bounds__(256) void te_main(
    const float* __restrict__ u, const float* __restrict__ v,
    const __bf16* __restrict__ w2t, const float* __restrict__ b2,
    float* __restrict__ out)
{
    __shared__ float vlds[6][H_];        // this block's 6 v-rows (3 KB)
    __shared__ float tbuf[4][16][64];    // per-wave output transpose tile (16 KB)

    int tid  = threadIdx.x;
    int wave = tid >> 6, lane = tid & 63;
    int g  = lane >> 4;        // lane group 0..3
    int rl = lane & 15;        // row-in-group

    int bid    = blockIdx.x;
    int mchunk = bid % 6;
    int t      = bid / 6;
    int ngrp   = t & 63;
    int b      = t >> 6;

    int m = mchunk * 64 + wave * 16 + rl;   // this lane's pair column (MFMA B col)

    // ---- stage v rows n = ngrp*6 .. +5 into LDS (192 threads x 16 B) ----
    if (tid < 192) {
        int row  = tid >> 5;           // 0..5
        int col4 = (tid & 31) << 2;    // 0,4,..,124
        *reinterpret_cast<f32x4*>(&vlds[row][col4]) =
            *reinterpret_cast<const f32x4*>(v + ((size_t)(b * N_ + ngrp * 6 + row)) * H_ + col4);
    }

    // --- loop-invariant register state (global loads, waited once) ---
    // W2^T fragments: w2f[rt][ks], element j holds W2[kk(ks,j,g)][rt*16+rl]
    // kk = ks*32 + (j>=4)*16 + g*4 + (j&3)
    bf16x8 w2f[4][4];
    #pragma unroll
    for (int rt = 0; rt < 4; ++rt) {
        const __bf16* basep = w2t + (rt * 16 + rl) * H_;
        #pragma unroll
        for (int ks = 0; ks < 4; ++ks) {
            #pragma unroll
            for (int hh = 0; hh < 2; ++hh) {
                bf16x4 q = *reinterpret_cast<const bf16x4*>(basep + ks * 32 + hh * 16 + g * 4);
                #pragma unroll
                for (int j = 0; j < 4; ++j) w2f[rt][ks][hh * 4 + j] = q[j];
            }
        }
    }

    // u[b, m, kk] fragments (fp32), fixed per wave
    f32x4 um[4][2];
    {
        const float* ub = u + ((size_t)(b * N_ + m)) * H_;
        #pragma unroll
        for (int ks = 0; ks < 4; ++ks)
            #pragma unroll
            for (int hh = 0; hh < 2; ++hh)
                um[ks][hh] = *reinterpret_cast<const f32x4*>(ub + ks * 32 + hh * 16 + g * 4);
    }

    // b2 fragments for accumulator init: lane's o = rt*16 + g*4 + reg
    f32x4 b2f[4];
    #pragma unroll
    for (int rt = 0; rt < 4; ++rt)
        b2f[rt] = *reinterpret_cast<const f32x4*>(b2 + rt * 16 + g * 4);

    __syncthreads();   // vlds ready

    size_t outb  = (size_t)b * N_ * N_ * DOUT_;
    float* tb    = &tbuf[wave][0][0];
    int    cblk2 = lane & 15;                 // read-side o-block (16B units)
    size_t mrow  = (size_t)(mchunk * 64 + wave * 16);  // wave's first m

    // Main loop: ds_read (lgkmcnt) + VALU + MFMA + LDS-transpose + coalesced
    // stores. No vector-memory LOADS -> stores are fire-and-forget.
    #pragma unroll 2
    for (int i = 0; i < 6; ++i) {
        int n = ngrp * 6 + i;

        // h fragments (B operand): lane holds h[kk][m] for its m
        bf16x8 hf[4];
        #pragma unroll
        for (int ks = 0; ks < 4; ++ks) {
            #pragma unroll
            for (int hh = 0; hh < 2; ++hh) {
                f32x4 vv = *reinterpret_cast<const f32x4*>(&vlds[i][ks * 32 + hh * 16 + g * 4]);
                #pragma unroll
                for (int j = 0; j < 4; ++j) {
                    float d  = vv[j] - um[ks][hh][j];
                    float hv = d > 0.f ? d : 0.f;
                    hf[ks][hh * 4 + j] = (__bf16)hv;
                }
            }
        }

        f32x4 acc[4];
        #pragma unroll
        for (int rt = 0; rt < 4; ++rt) acc[rt] = b2f[rt];

        #pragma unroll
        for (int ks = 0; ks < 4; ++ks)
            #pragma unroll
            for (int rt = 0; rt < 4; ++rt)
                acc[rt] = __builtin_amdgcn_mfma_f32_16x16x32_bf16(w2f[rt][ks], hf[ks], acc[rt], 0, 0, 0);

        // ---- per-wave LDS transpose (XOR block swizzle, bank-uniform) ----
        // write: lane (g,rl) holds o-block (rt*4+g) of row rl
        #pragma unroll
        for (int rt = 0; rt < 4; ++rt) {
            int cblk = ((rt << 2) | g) ^ rl;
            *reinterpret_cast<f32x4*>(tb + (rl << 6) + (cblk << 2)) = acc[rt];
        }
        // read rows back coalesced: lane ln -> row (ln>>4)|(q<<2), 16B @ (ln&15)
        float* onp = out + outb + ((size_t)n * N_ + mrow) * DOUT_;
        #pragma unroll
        for (int q = 0; q < 4; ++q) {
            int mm = (lane >> 4) | (q << 2);
            f32x4 rowv = *reinterpret_cast<const f32x4*>(tb + (mm << 6) + (((cblk2 ^ mm)) << 2));
            *reinterpret_cast<f32x4*>(onp + (size_t)mm * DOUT_ + (cblk2 << 2)) = rowv;
        }
    }
}

extern "C" void kernel_launch(void* const* d_in, const int* in_sizes, int n_in,
                              void* d_out, int out_size, void* d_ws, size_t ws_size,
                              hipStream_t stream)
{
    const float* r    = (const float*)d_in[0];
    const float* xctx = (const float*)d_in[1];
    // d_in[2] = y_ctx (unused), d_in[3] = x_trg (unused)
    const float* W1 = (const float*)d_in[4];
    const float* b1 = (const float*)d_in[5];
    const float* W2 = (const float*)d_in[6];
    const float* b2 = (const float*)d_in[7];
    float* out = (float*)d_out;

    char* ws = (char*)d_ws;   // needs ~1.6 MB
    float*  c   = (float*)(ws);
    float*  u   = (float*)(ws + 2048);
    float*  v   = (float*)(ws + 2048 + 786432);
    __bf16* w2t = (__bf16*)(ws + 2048 + 2 * 786432);

    hipLaunchKernelGGL(prep_c_w2, dim3(5), dim3(256), 0, stream, r, W1, b1, W2, c, w2t);
    hipLaunchKernelGGL(prep_uv, dim3(B_ * N_), dim3(128), 0, stream, xctx, W1, c, u, v);
    hipLaunchKernelGGL(te_main, dim3(B_ * 6 * 64), dim3(256), 0, stream, u, v, w2t, b2, out);
}

// Round 4
// 40.564 us; speedup vs baseline: 1.9262x; 1.3812x over previous
//
#include <hip/hip_runtime.h>

// Problem: B=4, N=384, DX=2, DR=128, H=128, DOUT=64
// out[b,n,m,o] = relu( (x_ctx[b,n]-x_ctx[b,m]) @ W1[0:2] + r[b] @ W1[2:130] + b1 ) @ W2 + b2
//
// Round-4: ONE fused kernel. Block = one (b,n) output row (grid 1536).
//   - c[b,k] = b1[k] + sum_d r[b,d] W1[2+d,k] recomputed per block
//     (identical arithmetic in every block -> deterministic).
//   - x_ctx[b] staged in LDS (3 KB); h_pre = dx0*W1[0,k]+dx1*W1[1,k]+c[k]
//     computed in-register per m-tile (matches reference x_diff@W1 form).
//   - W2^T fragments (bf16), W1-row/c/b2 fragments (f32) in registers.
//   - Main loop: LDS reads + VALU + 16 MFMA + per-wave LDS transpose +
//     4x1KB contiguous stores. ZERO global loads, ZERO barriers in loop.
//   - Each wave streams 24.5 KB ascending-contiguous; block covers a
//     contiguous 98 KB of out. Plain stores (out fits in 256MB L3).

typedef __attribute__((ext_vector_type(8))) __bf16 bf16x8;
typedef __attribute__((ext_vector_type(4))) float f32x4;

#define B_    4
#define N_    384
#define H_    128
#define DOUT_ 64

__global__ __launch_bounds__(256, 2) void te_fused(
    const float* __restrict__ r, const float* __restrict__ xctx,
    const float* __restrict__ W1, const float* __restrict__ b1,
    const float* __restrict__ W2, const float* __restrict__ b2,
    float* __restrict__ out)
{
    __shared__ __align__(16) float xs[N_ * 2];        // 3 KB  x_ctx[b]
    __shared__ __align__(16) float cpart[2][H_];      // 1 KB  c partials
    __shared__ __align__(16) float tbuf[4][16][64];   // 16 KB per-wave transpose

    const int tid  = threadIdx.x;
    const int wave = tid >> 6, lane = tid & 63;
    const int g = lane >> 4, rl = lane & 15;

    const int bid = blockIdx.x;
    const int b = bid / N_, n = bid - b * N_;

    // ---- prologue: c partial reduction (all 256 threads) ----
    {
        const int k = tid & 127, dh = tid >> 7;
        float acc = dh ? 0.f : b1[k];
        const float* wc = W1 + (2 + dh * 64) * H_ + k;
        const float* rb = r + b * 128 + dh * 64;
        #pragma unroll 8
        for (int d = 0; d < 64; ++d) acc = fmaf(rb[d], wc[d * H_], acc);
        cpart[dh][k] = acc;
    }
    // ---- stage x_ctx[b] (192 threads x 16 B) ----
    if (tid < 192)
        *reinterpret_cast<f32x4*>(&xs[tid * 4]) =
            *reinterpret_cast<const f32x4*>(xctx + b * (N_ * 2) + tid * 4);

    // ---- W2^T fragments: w2f[rt][ks][jj] = bf16(W2[kk][rt*16+rl]),
    //      kk = ks*32 + (jj>=4)*16 + g*4 + (jj&3)  (scalar gathers, L2-hit) ----
    bf16x8 w2f[4][4];
    #pragma unroll
    for (int rt = 0; rt < 4; ++rt) {
        const float* wp = W2 + rt * 16 + rl;   // + kk*64
        #pragma unroll
        for (int ks = 0; ks < 4; ++ks)
            #pragma unroll
            for (int jj = 0; jj < 8; ++jj) {
                const int kk = ks * 32 + ((jj >> 2) << 4) + (g << 2) + (jj & 3);
                w2f[rt][ks][jj] = (__bf16)wp[kk * DOUT_];
            }
    }

    // ---- W1 row-0/row-1 fragments + b2 fragments ----
    f32x4 w1a[4][2], w1b[4][2], cf[4][2], b2f[4];
    #pragma unroll
    for (int ks = 0; ks < 4; ++ks)
        #pragma unroll
        for (int hh = 0; hh < 2; ++hh) {
            const int kk = ks * 32 + hh * 16 + (g << 2);
            w1a[ks][hh] = *reinterpret_cast<const f32x4*>(W1 + kk);
            w1b[ks][hh] = *reinterpret_cast<const f32x4*>(W1 + H_ + kk);
        }
    #pragma unroll
    for (int rt = 0; rt < 4; ++rt)
        b2f[rt] = *reinterpret_cast<const f32x4*>(b2 + rt * 16 + (g << 2));

    __syncthreads();   // xs + cpart ready (only barrier in the kernel)

    // ---- c fragments ----
    #pragma unroll
    for (int ks = 0; ks < 4; ++ks)
        #pragma unroll
        for (int hh = 0; hh < 2; ++hh) {
            const int kk = ks * 32 + hh * 16 + (g << 2);
            cf[ks][hh] = *reinterpret_cast<const f32x4*>(&cpart[0][kk]) +
                         *reinterpret_cast<const f32x4*>(&cpart[1][kk]);
        }

    const float x0n = xs[2 * n], x1n = xs[2 * n + 1];
    float* tb = &tbuf[wave][0][0];
    const int cb2 = lane & 15;
    float* const outn = out + ((size_t)(b * N_ + n)) * N_ * DOUT_;

    // ---- main loop: wave w covers m in [w*96, w*96+96), 6 tiles of 16 ----
    for (int t = 0; t < 6; ++t) {
        const int mbase = wave * 96 + t * 16;
        const int m = mbase + rl;
        const float dx0 = x0n - xs[2 * m];
        const float dx1 = x1n - xs[2 * m + 1];

        bf16x8 hf[4];
        #pragma unroll
        for (int ks = 0; ks < 4; ++ks)
            #pragma unroll
            for (int hh = 0; hh < 2; ++hh)
                #pragma unroll
                for (int j = 0; j < 4; ++j) {
                    float hp = fmaf(dx1, w1b[ks][hh][j],
                               fmaf(dx0, w1a[ks][hh][j], cf[ks][hh][j]));
                    hf[ks][hh * 4 + j] = (__bf16)(hp > 0.f ? hp : 0.f);
                }

        f32x4 acc[4];
        #pragma unroll
        for (int rt = 0; rt < 4; ++rt) acc[rt] = b2f[rt];
        #pragma unroll
        for (int ks = 0; ks < 4; ++ks)
            #pragma unroll
            for (int rt = 0; rt < 4; ++rt)
                acc[rt] = __builtin_amdgcn_mfma_f32_16x16x32_bf16(w2f[rt][ks], hf[ks], acc[rt], 0, 0, 0);

        // per-wave LDS transpose (XOR block swizzle) -> 4 x 1KB contiguous stores
        #pragma unroll
        for (int rt = 0; rt < 4; ++rt) {
            const int cblk = ((rt << 2) | g) ^ rl;
            *reinterpret_cast<f32x4*>(tb + (rl << 6) + (cblk << 2)) = acc[rt];
        }
        float* onp = outn + (size_t)mbase * DOUT_;
        #pragma unroll
        for (int q = 0; q < 4; ++q) {
            const int mm = (lane >> 4) | (q << 2);
            f32x4 rowv = *reinterpret_cast<const f32x4*>(tb + (mm << 6) + ((cb2 ^ mm) << 2));
            *reinterpret_cast<f32x4*>(onp + mm * DOUT_ + (cb2 << 2)) = rowv;
        }
    }
}

extern "C" void kernel_launch(void* const* d_in, const int* in_sizes, int n_in,
                              void* d_out, int out_size, void* d_ws, size_t ws_size,
                              hipStream_t stream)
{
    const float* r    = (const float*)d_in[0];
    const float* xctx = (const float*)d_in[1];
    // d_in[2] = y_ctx (unused), d_in[3] = x_trg (unused)
    const float* W1 = (const float*)d_in[4];
    const float* b1 = (const float*)d_in[5];
    const float* W2 = (const float*)d_in[6];
    const float* b2 = (const float*)d_in[7];
    float* out = (float*)d_out;

    hipLaunchKernelGGL(te_fused, dim3(B_ * N_), dim3(256), 0, stream,
                       r, xctx, W1, b1, W2, b2, out);
}